// Round 11
// baseline (513.255 us; speedup 1.0000x reference)
//
#include <hip/hip_runtime.h>
#include <stdint.h>

// ---------- types ----------
typedef __attribute__((ext_vector_type(4))) float f32x4;
typedef __attribute__((ext_vector_type(8))) __bf16 bf8_t;     // MFMA A/B fragment (8 bf16 = 4 VGPR)
typedef __attribute__((ext_vector_type(8))) uint16_t u16x8;   // raw 16B bf16 load/store

typedef __attribute__((address_space(1))) uint8_t as1_u8;
typedef __attribute__((address_space(3))) uint8_t as3_u8;

__device__ inline void async_copy16(const void* g, void* l) {
  __builtin_amdgcn_global_load_lds((const as1_u8*)g, (as3_u8*)l, 16, 0, 0);
}

__device__ inline uint16_t f2bf(float f) {
  uint32_t u = __builtin_bit_cast(uint32_t, f);
  u = (u + 0x7fff + ((u >> 16) & 1)) >> 16;
  return (uint16_t)u;
}
__device__ inline float bf2f(uint16_t h) {
  uint32_t u = ((uint32_t)h) << 16;
  return __builtin_bit_cast(float, u);
}
// XOR swizzle for 256B-row bf16 LDS tiles (16 chunks of 16B per row)
__device__ inline int swz(int r) { return (((r & 7) ^ ((r >> 3) & 7)) << 4); }
// XOR swizzle for 128B-row bf16 LDS tiles (8 chunks of 16B per row)
__device__ inline int vswz(int r) { return ((r & 7) << 4); }

// ---------- rmsnorm: f32 [2048] row -> bf16 ----------
__global__ __launch_bounds__(256) void rmsnorm_kernel(const float* __restrict__ X,
                                                      const float* __restrict__ S,
                                                      uint16_t* __restrict__ O) {
  const int row = blockIdx.x;
  const int tid = threadIdx.x;
  const float* xr = X + (size_t)row * 2048;
  float4 v1 = ((const float4*)xr)[tid * 2];
  float4 v2 = ((const float4*)xr)[tid * 2 + 1];
  float ss = v1.x * v1.x + v1.y * v1.y + v1.z * v1.z + v1.w * v1.w +
             v2.x * v2.x + v2.y * v2.y + v2.z * v2.z + v2.w * v2.w;
  #pragma unroll
  for (int m = 1; m < 64; m <<= 1) ss += __shfl_xor(ss, m);
  __shared__ float wsum[4];
  if ((tid & 63) == 0) wsum[tid >> 6] = ss;
  __syncthreads();
  float tot = wsum[0] + wsum[1] + wsum[2] + wsum[3];
  float inv = rsqrtf(tot * (1.0f / 2048.0f) + 1e-5f);
  const int base = tid * 8;
  const float* sc = S + base;
  float xs[8] = {v1.x, v1.y, v1.z, v1.w, v2.x, v2.y, v2.z, v2.w};
  u16x8 o;
  #pragma unroll
  for (int j = 0; j < 8; j++) o[j] = f2bf(xs[j] * inv * sc[j]);
  *(u16x8*)(O + (size_t)row * 2048 + base) = o;
}

// ---------- transpose+convert body: W f32 [K][N] -> WT bf16 [N][K], one 64x64 tile ----------
__device__ inline void transpose_tile(const float* __restrict__ W, uint16_t* __restrict__ WT,
                                      int K, int N, int bx, int by, int tid) {
  __shared__ float tile[64][65];
  const int n0 = bx * 64, k0 = by * 64;
  const int lr = tid >> 4;
  const int lc = (tid & 15) * 4;
  #pragma unroll
  for (int i = 0; i < 4; i++) {
    const float4 v = *(const float4*)&W[(size_t)(k0 + lr + i * 16) * N + n0 + lc];
    tile[lr + i * 16][lc] = v.x;
    tile[lr + i * 16][lc + 1] = v.y;
    tile[lr + i * 16][lc + 2] = v.z;
    tile[lr + i * 16][lc + 3] = v.w;
  }
  __syncthreads();
  const int tn = tid >> 3;
  const int tk = (tid & 7) * 8;
  #pragma unroll
  for (int i = 0; i < 2; i++) {
    u16x8 o;
    #pragma unroll
    for (int j = 0; j < 8; j++) o[j] = f2bf(tile[tk + j][tn + i * 32]);
    *(u16x8*)&WT[(size_t)(n0 + tn + i * 32) * K + k0 + tk] = o;
  }
}

// one launch for all 5 weight transposes
__global__ __launch_bounds__(256) void transpose_all(
    const float* __restrict__ w_attn, const float* __restrict__ w_proj,
    const float* __restrict__ w_fc1, const float* __restrict__ w_fc2,
    const float* __restrict__ w_mp,
    uint16_t* __restrict__ wt_attn, uint16_t* __restrict__ wt_proj,
    uint16_t* __restrict__ wt_fc1, uint16_t* __restrict__ wt_fc2,
    uint16_t* __restrict__ wt_mp) {
  int idx = blockIdx.x;
  const int tid = threadIdx.x;
  if (idx < 3072) {                       // w_attn: 96 x 32 tiles
    transpose_tile(w_attn, wt_attn, 2048, 6144, idx % 96, idx / 96, tid);
  } else if (idx < 4096) {                // w_proj: 32 x 32
    idx -= 3072;
    transpose_tile(w_proj, wt_proj, 2048, 2048, idx % 32, idx / 32, tid);
  } else if (idx < 6912) {                // w_fc1: 88 x 32
    idx -= 4096;
    transpose_tile(w_fc1, wt_fc1, 2048, 5632, idx % 88, idx / 88, tid);
  } else if (idx < 9728) {                // w_fc2: 88 x 32
    idx -= 6912;
    transpose_tile(w_fc2, wt_fc2, 2048, 5632, idx % 88, idx / 88, tid);
  } else {                                // w_mp: 32 x 88 (K=5632)
    idx -= 9728;
    transpose_tile(w_mp, wt_mp, 5632, 2048, idx % 32, idx / 32, tid);
  }
}

// ---------- transpose V third of qkv: bf16 [2048 t][4096+c] -> vT [2048 c][2048 t] ----------
__global__ __launch_bounds__(256) void transpose_v(const uint16_t* __restrict__ qkv,
                                                   uint16_t* __restrict__ vT) {
  __shared__ uint16_t tile[64][68];
  const int t0 = blockIdx.x * 64;
  const int c0 = blockIdx.y * 64;
  const int tid = threadIdx.x;
  const int lr = tid >> 3;
  const int lc = (tid & 7) * 8;
  #pragma unroll
  for (int i = 0; i < 2; i++) {
    const int r = lr + i * 32;
    u16x8 v = *(const u16x8*)&qkv[(size_t)(t0 + r) * 6144 + 4096 + c0 + lc];
    #pragma unroll
    for (int j = 0; j < 8; j++) tile[lc + j][r] = v[j];
  }
  __syncthreads();
  #pragma unroll
  for (int i = 0; i < 2; i++) {
    const int c = lr + i * 32;
    u16x8 o = *(const u16x8*)&tile[c][lc];
    *(u16x8*)&vT[(size_t)(c0 + c) * 2048 + t0 + lc] = o;
  }
}

// ---------- GEMM epilogue modes ----------
enum { EPI_BF16 = 0, EPI_ADDF32 = 1, EPI_SILUMUL = 2 };

__device__ inline void gemm_epi(int EPI, void* Cout, const void* RES, size_t idx, float v) {
  if (EPI == EPI_BF16) {
    ((uint16_t*)Cout)[idx] = f2bf(v);
  } else if (EPI == EPI_ADDF32) {
    ((float*)Cout)[idx] = ((const float*)RES)[idx] + v;
  } else {
    const float g = bf2f(((const uint16_t*)RES)[idx]);
    const float sg = g / (1.0f + __expf(-g));
    ((uint16_t*)Cout)[idx] = f2bf(sg * v);
  }
}

// ---------- 128x128 GEMM, BK=128 (quartered drains vs BK=32; swizzled LDS) ----------
// 256B rows = 16 chunks of 16B; store lds[row][c] = global[row][c ^ (row&7)]
// (XOR on low 3 bits of chunk index, rule 21); read chunk (ks*4+l4)^(R&7).
// Bank check: 16 lanes -> 8 distinct chunks x 2 = 2-way conflict (free, m136).
template <int EPI>
__global__ __launch_bounds__(256, 2) void gemm_bt(const uint16_t* __restrict__ A,
                                                  const uint16_t* __restrict__ BT,
                                                  void* __restrict__ Cout,
                                                  const void* __restrict__ RES,
                                                  int M, int N, int K) {
  __shared__ uint16_t As[128 * 128];  // 32 KB
  __shared__ uint16_t Bs[128 * 128];  // 32 KB
  const int tid = threadIdx.x;
  const int lane = tid & 63;
  const int w = tid >> 6;
  const int l15 = lane & 15, l4 = lane >> 4;
  const int m0 = blockIdx.y * 128, n0 = blockIdx.x * 128;
  const int wr = w >> 1, wc = w & 1;

  f32x4 acc[4][4];
  #pragma unroll
  for (int i = 0; i < 4; i++)
    #pragma unroll
    for (int j = 0; j < 4; j++) acc[i][j] = 0.0f;

  for (int kk = 0; kk < K; kk += 128) {
    __syncthreads();
    #pragma unroll
    for (int s = 0; s < 8; s++) {
      const int bu = s * 256 + w * 64;     // wave-uniform 16B-chunk base
      const int u = bu + lane;             // chunk 0..2047
      const int row = u >> 4;              // 16 chunks/row
      const int ch = (u & 15) ^ (row & 7); // pre-swizzled source chunk
      async_copy16(A + (size_t)(m0 + row) * K + kk + ch * 8, (char*)As + bu * 16);
      async_copy16(BT + (size_t)(n0 + row) * K + kk + ch * 8, (char*)Bs + bu * 16);
    }
    __syncthreads();
    #pragma unroll
    for (int ks = 0; ks < 4; ks++) {
      bf8_t a[4], b[4];
      #pragma unroll
      for (int mi = 0; mi < 4; mi++) {
        const int R = wr * 64 + mi * 16 + l15;
        a[mi] = *(const bf8_t*)((const char*)As + R * 256 + (((ks * 4 + l4) ^ (R & 7)) * 16));
      }
      #pragma unroll
      for (int ni = 0; ni < 4; ni++) {
        const int R = wc * 64 + ni * 16 + l15;
        b[ni] = *(const bf8_t*)((const char*)Bs + R * 256 + (((ks * 4 + l4) ^ (R & 7)) * 16));
      }
      #pragma unroll
      for (int mi = 0; mi < 4; mi++)
        #pragma unroll
        for (int ni = 0; ni < 4; ni++)
          acc[mi][ni] = __builtin_amdgcn_mfma_f32_16x16x32_bf16(a[mi], b[ni], acc[mi][ni], 0, 0, 0);
    }
  }

  #pragma unroll
  for (int mi = 0; mi < 4; mi++) {
    #pragma unroll
    for (int ni = 0; ni < 4; ni++) {
      #pragma unroll
      for (int r = 0; r < 4; r++) {
        const int row = m0 + wr * 64 + mi * 16 + l4 * 4 + r;
        const int col = n0 + wc * 64 + ni * 16 + l15;
        gemm_epi(EPI, Cout, RES, (size_t)row * N + col, acc[mi][ni][r]);
      }
    }
  }
}

// ---------- 128x64-tile GEMM, BK=128, for N=2048 outputs (proj / mlp_proj) ----------
template <int EPI>
__global__ __launch_bounds__(256, 3) void gemm_bt64(const uint16_t* __restrict__ A,
                                                    const uint16_t* __restrict__ BT,
                                                    void* __restrict__ Cout,
                                                    const void* __restrict__ RES,
                                                    int M, int N, int K) {
  __shared__ uint16_t As[128 * 128];  // 32 KB
  __shared__ uint16_t Bs[64 * 128];   // 16 KB
  const int tid = threadIdx.x;
  const int lane = tid & 63;
  const int w = tid >> 6;
  const int l15 = lane & 15, l4 = lane >> 4;
  const int m0 = blockIdx.y * 128, n0 = blockIdx.x * 64;

  f32x4 acc[2][4];
  #pragma unroll
  for (int i = 0; i < 2; i++)
    #pragma unroll
    for (int j = 0; j < 4; j++) acc[i][j] = 0.0f;

  for (int kk = 0; kk < K; kk += 128) {
    __syncthreads();
    #pragma unroll
    for (int s = 0; s < 8; s++) {
      const int bu = s * 256 + w * 64;
      const int u = bu + lane;
      const int row = u >> 4;
      const int ch = (u & 15) ^ (row & 7);
      async_copy16(A + (size_t)(m0 + row) * K + kk + ch * 8, (char*)As + bu * 16);
    }
    #pragma unroll
    for (int s = 0; s < 4; s++) {
      const int bu = s * 256 + w * 64;
      const int u = bu + lane;
      const int row = u >> 4;              // 0..63
      const int ch = (u & 15) ^ (row & 7);
      async_copy16(BT + (size_t)(n0 + row) * K + kk + ch * 8, (char*)Bs + bu * 16);
    }
    __syncthreads();
    #pragma unroll
    for (int ks = 0; ks < 4; ks++) {
      bf8_t a[2], b[4];
      #pragma unroll
      for (int mi = 0; mi < 2; mi++) {
        const int R = w * 32 + mi * 16 + l15;
        a[mi] = *(const bf8_t*)((const char*)As + R * 256 + (((ks * 4 + l4) ^ (R & 7)) * 16));
      }
      #pragma unroll
      for (int ni = 0; ni < 4; ni++) {
        const int R = ni * 16 + l15;
        b[ni] = *(const bf8_t*)((const char*)Bs + R * 256 + (((ks * 4 + l4) ^ (R & 7)) * 16));
      }
      #pragma unroll
      for (int mi = 0; mi < 2; mi++)
        #pragma unroll
        for (int ni = 0; ni < 4; ni++)
          acc[mi][ni] = __builtin_amdgcn_mfma_f32_16x16x32_bf16(a[mi], b[ni], acc[mi][ni], 0, 0, 0);
    }
  }

  #pragma unroll
  for (int mi = 0; mi < 2; mi++) {
    #pragma unroll
    for (int ni = 0; ni < 4; ni++) {
      #pragma unroll
      for (int r = 0; r < 4; r++) {
        const int row = m0 + w * 32 + mi * 16 + l4 * 4 + r;
        const int col = n0 + ni * 16 + l15;
        gemm_epi(EPI, Cout, RES, (size_t)row * N + col, acc[mi][ni][r]);
      }
    }
  }
}

// ---------- flash attention, kv-split partials (unchanged from R8/R10) ----------
#define PART_STRIDE (64 * 128 + 128)
__global__ __launch_bounds__(256, 2) void attn_part(const uint16_t* __restrict__ qkv,
                                                    const uint16_t* __restrict__ vT,
                                                    const float* __restrict__ alibi,
                                                    float* __restrict__ part) {
  const int p = blockIdx.x;
  const int qt = 31 - blockIdx.y;
  const int h = blockIdx.z;
  const int c = (qt + 4) >> 2;
  const int start = p * c;
  const int end = min((p + 1) * c, qt + 1);
  if (start >= end) return;

  const int tid = threadIdx.x;
  const int lane = tid & 63;
  const int w = tid >> 6;
  const int l15 = lane & 15, l4 = lane >> 4;

  __shared__ uint16_t Ks[2][64 * 128];
  __shared__ uint16_t Vs[2][128 * 64];
  __shared__ uint16_t Ps[4][16 * 64];

  const float scale = 0.08838834764831845f;

  auto stage = [&](int kv0, int b) {
    #pragma unroll
    for (int i = 0; i < 4; i++) {
      const int u = tid + i * 256;
      const int r = u >> 4;
      const int cc = (u & 15) ^ ((r & 7) ^ ((r >> 3) & 7));
      async_copy16(qkv + (size_t)(kv0 + r) * 6144 + 2048 + h * 128 + cc * 8,
                   (char*)Ks[b] + u * 16);
    }
    #pragma unroll
    for (int i = 0; i < 4; i++) {
      const int u = tid + i * 256;
      const int r = u >> 3;
      const int cc = (u & 7) ^ (r & 7);
      async_copy16(vT + (size_t)(h * 128 + r) * 2048 + kv0 + cc * 8,
                   (char*)Vs[b] + u * 16);
    }
  };
  auto load_al = [&](int kv0, float (&al)[4][4]) {
    #pragma unroll
    for (int r = 0; r < 4; r++) {
      const size_t rowb = ((size_t)h * 2048 + (qt * 64 + w * 16 + l4 * 4 + r)) * 2048;
      #pragma unroll
      for (int nf = 0; nf < 4; nf++)
        al[nf][r] = alibi[rowb + kv0 + nf * 16 + l15];
    }
  };

  const int qrow = qt * 64 + w * 16 + l15;
  bf8_t qf[4];
  #pragma unroll
  for (int kc = 0; kc < 4; kc++)
    qf[kc] = *(const bf8_t*)(qkv + (size_t)qrow * 6144 + h * 128 + kc * 32 + l4 * 8);

  f32x4 accy[8];
  #pragma unroll
  for (int i = 0; i < 8; i++) accy[i] = 0.0f;
  float mrun[4], lrun[4];
  #pragma unroll
  for (int r = 0; r < 4; r++) { mrun[r] = -1e30f; lrun[r] = 0.0f; }

  stage(start * 64, 0);
  float al[4][4];
  load_al(start * 64, al);

  for (int kvt = start; kvt < end; kvt++) {
    const int b = (kvt - start) & 1;
    const int kv0 = kvt * 64;
    __syncthreads();

    const int kvn = (kvt + 1 < end) ? (kvt + 1) : kvt;
    float aln[4][4];
    load_al(kvn * 64, aln);
    stage(kvn * 64, b ^ 1);

    float s[4][4];
    #pragma unroll
    for (int nf = 0; nf < 4; nf++) {
      f32x4 sa = 0.0f;
      const int krow = nf * 16 + l15;
      __builtin_amdgcn_s_setprio(1);
      #pragma unroll
      for (int kc = 0; kc < 4; kc++) {
        bf8_t kb = *(const bf8_t*)((const char*)Ks[b] +
                                   ((krow * 256 + kc * 64 + l4 * 16) ^ swz(krow)));
        sa = __builtin_amdgcn_mfma_f32_16x16x32_bf16(qf[kc], kb, sa, 0, 0, 0);
      }
      __builtin_amdgcn_s_setprio(0);
      const int kvcol = kv0 + nf * 16 + l15;
      #pragma unroll
      for (int r = 0; r < 4; r++) {
        const int q = qt * 64 + w * 16 + l4 * 4 + r;
        float sv = sa[r] * scale + al[nf][r];
        if (kvcol > q) sv = -1e30f;
        s[nf][r] = sv;
      }
    }

    #pragma unroll
    for (int r = 0; r < 4; r++) {
      float rm = fmaxf(fmaxf(s[0][r], s[1][r]), fmaxf(s[2][r], s[3][r]));
      rm = fmaxf(rm, __shfl_xor(rm, 1));
      rm = fmaxf(rm, __shfl_xor(rm, 2));
      rm = fmaxf(rm, __shfl_xor(rm, 4));
      rm = fmaxf(rm, __shfl_xor(rm, 8));
      const float mnew = fmaxf(mrun[r], rm);
      const float alpha = __expf(mrun[r] - mnew);
      mrun[r] = mnew;
      float rs = 0.0f;
      #pragma unroll
      for (int nf = 0; nf < 4; nf++) {
        const float pp = __expf(s[nf][r] - mnew);
        s[nf][r] = pp;
        rs += pp;
      }
      rs += __shfl_xor(rs, 1);
      rs += __shfl_xor(rs, 2);
      rs += __shfl_xor(rs, 4);
      rs += __shfl_xor(rs, 8);
      lrun[r] = lrun[r] * alpha + rs;
      #pragma unroll
      for (int df = 0; df < 8; df++) accy[df][r] *= alpha;
    }

    #pragma unroll
    for (int nf = 0; nf < 4; nf++) {
      #pragma unroll
      for (int r = 0; r < 4; r++) {
        const int rq = l4 * 4 + r;
        const int bo = (rq * 128 + (nf * 16 + l15) * 2) ^ vswz(rq);
        *(uint16_t*)((char*)Ps[w] + bo) = f2bf(s[nf][r]);
      }
    }

    __builtin_amdgcn_s_setprio(1);
    #pragma unroll
    for (int kk = 0; kk < 2; kk++) {
      bf8_t pa = *(const bf8_t*)((const char*)Ps[w] +
                                 ((l15 * 128 + kk * 64 + l4 * 16) ^ vswz(l15)));
      #pragma unroll
      for (int df = 0; df < 8; df++) {
        const int vr = df * 16 + l15;
        bf8_t vb = *(const bf8_t*)((const char*)Vs[b] +
                                   ((vr * 128 + kk * 64 + l4 * 16) ^ vswz(vr)));
        accy[df] = __builtin_amdgcn_mfma_f32_16x16x32_bf16(pa, vb, accy[df], 0, 0, 0);
      }
    }
    __builtin_amdgcn_s_setprio(0);

    #pragma unroll
    for (int nf = 0; nf < 4; nf++)
      #pragma unroll
      for (int r = 0; r < 4; r++) al[nf][r] = aln[nf][r];
  }

  float* pb = part + (size_t)(((h * 32 + qt) * 4) + p) * PART_STRIDE;
  #pragma unroll
  for (int df = 0; df < 8; df++) {
    #pragma unroll
    for (int r = 0; r < 4; r++) {
      const int row = w * 16 + l4 * 4 + r;
      pb[row * 128 + df * 16 + l15] = accy[df][r];
    }
  }
  if (l15 == 0) {
    #pragma unroll
    for (int r = 0; r < 4; r++) {
      const int row = w * 16 + l4 * 4 + r;
      pb[8192 + row] = mrun[r];
      pb[8192 + 64 + row] = lrun[r];
    }
  }
}

// ---------- merge kv-split partials -> Y bf16 [2048][2048] ----------
__global__ __launch_bounds__(256) void attn_merge(const float* __restrict__ part,
                                                  uint16_t* __restrict__ Y) {
  const int qt = blockIdx.x;
  const int h = blockIdx.y;
  const int c = (qt + 4) >> 2;
  const int cnt = (qt + c) / c;
  const int tid = threadIdx.x;
  const int row = tid >> 2;
  const int cg = (tid & 3) * 32;

  const float* pb = part + (size_t)((h * 32 + qt) * 4) * PART_STRIDE;

  float m_p[4], w_p[4];
  float M = -1e30f;
  for (int p = 0; p < cnt; p++) {
    m_p[p] = pb[p * PART_STRIDE + 8192 + row];
    M = fmaxf(M, m_p[p]);
  }
  float L = 0.0f;
  for (int p = 0; p < cnt; p++) {
    w_p[p] = __expf(m_p[p] - M);
    L += w_p[p] * pb[p * PART_STRIDE + 8192 + 64 + row];
  }
  const float invL = 1.0f / L;

  uint16_t* yr = Y + (size_t)(qt * 64 + row) * 2048 + h * 128 + cg;
  #pragma unroll
  for (int j = 0; j < 32; j += 8) {
    f32x4 s0 = 0.0f, s1 = 0.0f;
    for (int p = 0; p < cnt; p++) {
      const float* ap = pb + p * PART_STRIDE + row * 128 + cg + j;
      s0 += w_p[p] * *(const f32x4*)ap;
      s1 += w_p[p] * *(const f32x4*)(ap + 4);
    }
    u16x8 o;
    #pragma unroll
    for (int e = 0; e < 4; e++) { o[e] = f2bf(s0[e] * invL); o[e + 4] = f2bf(s1[e] * invL); }
    *(u16x8*)(yr + j) = o;
  }
}

// ---------- launch ----------
extern "C" void kernel_launch(void* const* d_in, const int* in_sizes, int n_in,
                              void* d_out, int out_size, void* d_ws, size_t ws_size,
                              hipStream_t stream) {
  const float* x      = (const float*)d_in[0];
  const float* alibi  = (const float*)d_in[1];
  const float* w_attn = (const float*)d_in[2];
  const float* w_proj = (const float*)d_in[3];
  const float* w_fc1  = (const float*)d_in[4];
  const float* w_fc2  = (const float*)d_in[5];
  const float* w_mp   = (const float*)d_in[6];
  const float* rms1   = (const float*)d_in[7];
  const float* rms2   = (const float*)d_in[8];
  float* out = (float*)d_out;

  char* ws = (char*)d_ws;
  uint16_t* xn      = (uint16_t*)(ws + 0);
  uint16_t* qkv     = (uint16_t*)(ws + 8388608);
  uint16_t* y       = (uint16_t*)(ws + 33554432);
  uint16_t* g1      = (uint16_t*)(ws + 41943040);
  uint16_t* hbuf    = (uint16_t*)(ws + 65011712);
  uint16_t* wt_attn = (uint16_t*)(ws + 88080384);
  uint16_t* wt_proj = (uint16_t*)(ws + 113246208);
  uint16_t* wt_fc1  = (uint16_t*)(ws + 121634816);
  uint16_t* wt_fc2  = (uint16_t*)(ws + 144703488);
  uint16_t* wt_mp   = (uint16_t*)(ws + 167772160);
  uint16_t* vT      = (uint16_t*)(ws + 190840832);
  float*    part    = (float*)(ws + 199229440);

  transpose_all<<<12544, 256, 0, stream>>>(w_attn, w_proj, w_fc1, w_fc2, w_mp,
                                           wt_attn, wt_proj, wt_fc1, wt_fc2, wt_mp);

  rmsnorm_kernel<<<2048, 256, 0, stream>>>(x, rms1, xn);

  gemm_bt<EPI_BF16><<<dim3(6144 / 128, 2048 / 128), 256, 0, stream>>>(
      xn, wt_attn, qkv, nullptr, 2048, 6144, 2048);

  transpose_v<<<dim3(32, 32), 256, 0, stream>>>(qkv, vT);

  attn_part<<<dim3(4, 32, 16), 256, 0, stream>>>(qkv, vT, alibi, part);

  attn_merge<<<dim3(32, 16), 256, 0, stream>>>(part, y);

  gemm_bt64<EPI_ADDF32><<<dim3(2048 / 64, 2048 / 128), 256, 0, stream>>>(
      y, wt_proj, out, x, 2048, 2048, 2048);

  rmsnorm_kernel<<<2048, 256, 0, stream>>>(out, rms2, xn);

  gemm_bt<EPI_BF16><<<dim3(5632 / 128, 2048 / 128), 256, 0, stream>>>(
      xn, wt_fc1, g1, nullptr, 2048, 5632, 2048);

  gemm_bt<EPI_SILUMUL><<<dim3(5632 / 128, 2048 / 128), 256, 0, stream>>>(
      xn, wt_fc2, hbuf, g1, 2048, 5632, 2048);

  gemm_bt64<EPI_ADDF32><<<dim3(2048 / 64, 2048 / 128), 256, 0, stream>>>(
      hbuf, wt_mp, out, out, 2048, 2048, 5632);
}

// Round 12
// 477.506 us; speedup vs baseline: 1.0749x; 1.0749x over previous
//
#include <hip/hip_runtime.h>
#include <stdint.h>

// ---------- types ----------
typedef __attribute__((ext_vector_type(4))) float f32x4;
typedef __attribute__((ext_vector_type(8))) __bf16 bf8_t;     // MFMA A/B fragment (8 bf16 = 4 VGPR)
typedef __attribute__((ext_vector_type(8))) uint16_t u16x8;   // raw 16B bf16 load/store

typedef __attribute__((address_space(1))) uint8_t as1_u8;
typedef __attribute__((address_space(3))) uint8_t as3_u8;

__device__ inline void async_copy16(const void* g, void* l) {
  __builtin_amdgcn_global_load_lds((const as1_u8*)g, (as3_u8*)l, 16, 0, 0);
}

__device__ inline uint16_t f2bf(float f) {
  uint32_t u = __builtin_bit_cast(uint32_t, f);
  u = (u + 0x7fff + ((u >> 16) & 1)) >> 16;
  return (uint16_t)u;
}
__device__ inline float bf2f(uint16_t h) {
  uint32_t u = ((uint32_t)h) << 16;
  return __builtin_bit_cast(float, u);
}
// XOR swizzle for 256B-row bf16 LDS tiles (16 chunks of 16B per row)
__device__ inline int swz(int r) { return (((r & 7) ^ ((r >> 3) & 7)) << 4); }
// XOR swizzle for 128B-row bf16 LDS tiles (8 chunks of 16B per row)
__device__ inline int vswz(int r) { return ((r & 7) << 4); }

// ---------- rmsnorm: f32 [2048] row -> bf16 ----------
__global__ __launch_bounds__(256) void rmsnorm_kernel(const float* __restrict__ X,
                                                      const float* __restrict__ S,
                                                      uint16_t* __restrict__ O) {
  const int row = blockIdx.x;
  const int tid = threadIdx.x;
  const float* xr = X + (size_t)row * 2048;
  float4 v1 = ((const float4*)xr)[tid * 2];
  float4 v2 = ((const float4*)xr)[tid * 2 + 1];
  float ss = v1.x * v1.x + v1.y * v1.y + v1.z * v1.z + v1.w * v1.w +
             v2.x * v2.x + v2.y * v2.y + v2.z * v2.z + v2.w * v2.w;
  #pragma unroll
  for (int m = 1; m < 64; m <<= 1) ss += __shfl_xor(ss, m);
  __shared__ float wsum[4];
  if ((tid & 63) == 0) wsum[tid >> 6] = ss;
  __syncthreads();
  float tot = wsum[0] + wsum[1] + wsum[2] + wsum[3];
  float inv = rsqrtf(tot * (1.0f / 2048.0f) + 1e-5f);
  const int base = tid * 8;
  const float* sc = S + base;
  float xs[8] = {v1.x, v1.y, v1.z, v1.w, v2.x, v2.y, v2.z, v2.w};
  u16x8 o;
  #pragma unroll
  for (int j = 0; j < 8; j++) o[j] = f2bf(xs[j] * inv * sc[j]);
  *(u16x8*)(O + (size_t)row * 2048 + base) = o;
}

// ---------- transpose+convert: one 64x64 tile; catoff<0 -> linear rows,
// else interleaved-cat row: catrow = (n>>4)*32 + catoff + (n&15) ----------
__device__ inline void transpose_tile2(const float* __restrict__ W, uint16_t* __restrict__ WT,
                                       int K, int N, int bx, int by, int tid, int catoff) {
  __shared__ float tile[64][65];
  const int n0 = bx * 64, k0 = by * 64;
  const int lr = tid >> 4;
  const int lc = (tid & 15) * 4;
  #pragma unroll
  for (int i = 0; i < 4; i++) {
    const float4 v = *(const float4*)&W[(size_t)(k0 + lr + i * 16) * N + n0 + lc];
    tile[lr + i * 16][lc] = v.x;
    tile[lr + i * 16][lc + 1] = v.y;
    tile[lr + i * 16][lc + 2] = v.z;
    tile[lr + i * 16][lc + 3] = v.w;
  }
  __syncthreads();
  const int tn = tid >> 3;
  const int tk = (tid & 7) * 8;
  #pragma unroll
  for (int i = 0; i < 2; i++) {
    u16x8 o;
    #pragma unroll
    for (int j = 0; j < 8; j++) o[j] = f2bf(tile[tk + j][tn + i * 32]);
    const int n = n0 + tn + i * 32;
    const int row = (catoff < 0) ? n : (((n >> 4) << 5) + catoff + (n & 15));
    *(u16x8*)&WT[(size_t)row * K + k0 + tk] = o;
  }
}

// one launch for all 5 weight transposes (fc1/fc2 -> interleaved wt_cat)
__global__ __launch_bounds__(256) void transpose_all(
    const float* __restrict__ w_attn, const float* __restrict__ w_proj,
    const float* __restrict__ w_fc1, const float* __restrict__ w_fc2,
    const float* __restrict__ w_mp,
    uint16_t* __restrict__ wt_attn, uint16_t* __restrict__ wt_proj,
    uint16_t* __restrict__ wt_cat, uint16_t* __restrict__ wt_mp) {
  int idx = blockIdx.x;
  const int tid = threadIdx.x;
  if (idx < 3072) {                       // w_attn: 96 x 32 tiles
    transpose_tile2(w_attn, wt_attn, 2048, 6144, idx % 96, idx / 96, tid, -1);
  } else if (idx < 4096) {                // w_proj: 32 x 32
    idx -= 3072;
    transpose_tile2(w_proj, wt_proj, 2048, 2048, idx % 32, idx / 32, tid, -1);
  } else if (idx < 6912) {                // w_fc1: 88 x 32 -> cat even 16-groups
    idx -= 4096;
    transpose_tile2(w_fc1, wt_cat, 2048, 5632, idx % 88, idx / 88, tid, 0);
  } else if (idx < 9728) {                // w_fc2: 88 x 32 -> cat odd 16-groups
    idx -= 6912;
    transpose_tile2(w_fc2, wt_cat, 2048, 5632, idx % 88, idx / 88, tid, 16);
  } else {                                // w_mp: 32 x 88 (K=5632)
    idx -= 9728;
    transpose_tile2(w_mp, wt_mp, 5632, 2048, idx % 32, idx / 32, tid, -1);
  }
}

// ---------- transpose V third of qkv: bf16 [2048 t][4096+c] -> vT [2048 c][2048 t] ----------
__global__ __launch_bounds__(256) void transpose_v(const uint16_t* __restrict__ qkv,
                                                   uint16_t* __restrict__ vT) {
  __shared__ uint16_t tile[64][68];
  const int t0 = blockIdx.x * 64;
  const int c0 = blockIdx.y * 64;
  const int tid = threadIdx.x;
  const int lr = tid >> 3;
  const int lc = (tid & 7) * 8;
  #pragma unroll
  for (int i = 0; i < 2; i++) {
    const int r = lr + i * 32;
    u16x8 v = *(const u16x8*)&qkv[(size_t)(t0 + r) * 6144 + 4096 + c0 + lc];
    #pragma unroll
    for (int j = 0; j < 8; j++) tile[lc + j][r] = v[j];
  }
  __syncthreads();
  #pragma unroll
  for (int i = 0; i < 2; i++) {
    const int c = lr + i * 32;
    u16x8 o = *(const u16x8*)&tile[c][lc];
    *(u16x8*)&vT[(size_t)(c0 + c) * 2048 + t0 + lc] = o;
  }
}

// ---------- GEMM epilogue modes ----------
enum { EPI_BF16 = 0, EPI_ADDF32 = 1, EPI_SILUMUL = 2 };

__device__ inline void gemm_epi(int EPI, void* Cout, const void* RES, size_t idx, float v) {
  if (EPI == EPI_BF16) {
    ((uint16_t*)Cout)[idx] = f2bf(v);
  } else if (EPI == EPI_ADDF32) {
    ((float*)Cout)[idx] = ((const float*)RES)[idx] + v;
  } else {
    const float g = bf2f(((const uint16_t*)RES)[idx]);
    const float sg = g / (1.0f + __expf(-g));
    ((uint16_t*)Cout)[idx] = f2bf(sg * v);
  }
}

// ---------- 128x128 GEMM, BK=64 (R10 optimum: halved drains + swizzled LDS) ----------
template <int EPI>
__global__ __launch_bounds__(256, 2) void gemm_bt(const uint16_t* __restrict__ A,
                                                  const uint16_t* __restrict__ BT,
                                                  void* __restrict__ Cout,
                                                  const void* __restrict__ RES,
                                                  int M, int N, int K) {
  __shared__ uint16_t As[128 * 64];  // 16 KB
  __shared__ uint16_t Bs[128 * 64];  // 16 KB
  const int tid = threadIdx.x;
  const int lane = tid & 63;
  const int w = tid >> 6;
  const int l15 = lane & 15, l4 = lane >> 4;
  const int m0 = blockIdx.y * 128, n0 = blockIdx.x * 128;
  const int wr = w >> 1, wc = w & 1;

  f32x4 acc[4][4];
  #pragma unroll
  for (int i = 0; i < 4; i++)
    #pragma unroll
    for (int j = 0; j < 4; j++) acc[i][j] = 0.0f;

  for (int kk = 0; kk < K; kk += 64) {
    __syncthreads();
    #pragma unroll
    for (int s = 0; s < 4; s++) {
      const int bu = s * 256 + w * 64;     // wave-uniform 16B-chunk base
      const int u = bu + lane;             // chunk 0..1023
      const int row = u >> 3;
      const int ch = (u & 7) ^ (row & 7);  // pre-swizzled source chunk
      async_copy16(A + (size_t)(m0 + row) * K + kk + ch * 8, (char*)As + bu * 16);
      async_copy16(BT + (size_t)(n0 + row) * K + kk + ch * 8, (char*)Bs + bu * 16);
    }
    __syncthreads();
    bf8_t a[4][2], b[4][2];
    #pragma unroll
    for (int mi = 0; mi < 4; mi++)
      #pragma unroll
      for (int ks = 0; ks < 2; ks++) {
        const int R = wr * 64 + mi * 16 + l15;
        a[mi][ks] = *(const bf8_t*)((const char*)As + R * 128 + (((ks * 4 + l4) ^ (R & 7)) * 16));
      }
    #pragma unroll
    for (int ni = 0; ni < 4; ni++)
      #pragma unroll
      for (int ks = 0; ks < 2; ks++) {
        const int R = wc * 64 + ni * 16 + l15;
        b[ni][ks] = *(const bf8_t*)((const char*)Bs + R * 128 + (((ks * 4 + l4) ^ (R & 7)) * 16));
      }
    #pragma unroll
    for (int mi = 0; mi < 4; mi++)
      #pragma unroll
      for (int ni = 0; ni < 4; ni++)
        #pragma unroll
        for (int ks = 0; ks < 2; ks++)
          acc[mi][ni] = __builtin_amdgcn_mfma_f32_16x16x32_bf16(a[mi][ks], b[ni][ks],
                                                                acc[mi][ni], 0, 0, 0);
  }

  #pragma unroll
  for (int mi = 0; mi < 4; mi++) {
    #pragma unroll
    for (int ni = 0; ni < 4; ni++) {
      #pragma unroll
      for (int r = 0; r < 4; r++) {
        const int row = m0 + wr * 64 + mi * 16 + l4 * 4 + r;
        const int col = n0 + wc * 64 + ni * 16 + l15;
        gemm_epi(EPI, Cout, RES, (size_t)row * N + col, acc[mi][ni][r]);
      }
    }
  }
}

// ---------- fused fc1+fc2: C = silu(A@W1) * (A@W2) over interleaved wt_cat ----------
// BT = wt_cat [11264][2048]; cat row G*32+j: j<16 -> fc1 col G*16+j, j>=16 -> fc2.
// Within a 128-col cat tile, pairs (ni even, ni odd) are matched fc1/fc2 cols
// of hidden col n0/2 + ((wc*4+ni)>>1)*16 + l15. Output hbuf [2048][5632] bf16.
__global__ __launch_bounds__(256, 2) void gemm_cat(const uint16_t* __restrict__ A,
                                                   const uint16_t* __restrict__ BT,
                                                   uint16_t* __restrict__ Cout,
                                                   int M, int K) {
  __shared__ uint16_t As[128 * 64];
  __shared__ uint16_t Bs[128 * 64];
  const int tid = threadIdx.x;
  const int lane = tid & 63;
  const int w = tid >> 6;
  const int l15 = lane & 15, l4 = lane >> 4;
  const int m0 = blockIdx.y * 128, n0 = blockIdx.x * 128;  // n0 in cat space
  const int wr = w >> 1, wc = w & 1;

  f32x4 acc[4][4];
  #pragma unroll
  for (int i = 0; i < 4; i++)
    #pragma unroll
    for (int j = 0; j < 4; j++) acc[i][j] = 0.0f;

  for (int kk = 0; kk < K; kk += 64) {
    __syncthreads();
    #pragma unroll
    for (int s = 0; s < 4; s++) {
      const int bu = s * 256 + w * 64;
      const int u = bu + lane;
      const int row = u >> 3;
      const int ch = (u & 7) ^ (row & 7);
      async_copy16(A + (size_t)(m0 + row) * K + kk + ch * 8, (char*)As + bu * 16);
      async_copy16(BT + (size_t)(n0 + row) * K + kk + ch * 8, (char*)Bs + bu * 16);
    }
    __syncthreads();
    bf8_t a[4][2], b[4][2];
    #pragma unroll
    for (int mi = 0; mi < 4; mi++)
      #pragma unroll
      for (int ks = 0; ks < 2; ks++) {
        const int R = wr * 64 + mi * 16 + l15;
        a[mi][ks] = *(const bf8_t*)((const char*)As + R * 128 + (((ks * 4 + l4) ^ (R & 7)) * 16));
      }
    #pragma unroll
    for (int ni = 0; ni < 4; ni++)
      #pragma unroll
      for (int ks = 0; ks < 2; ks++) {
        const int R = wc * 64 + ni * 16 + l15;
        b[ni][ks] = *(const bf8_t*)((const char*)Bs + R * 128 + (((ks * 4 + l4) ^ (R & 7)) * 16));
      }
    #pragma unroll
    for (int mi = 0; mi < 4; mi++)
      #pragma unroll
      for (int ni = 0; ni < 4; ni++)
        #pragma unroll
        for (int ks = 0; ks < 2; ks++)
          acc[mi][ni] = __builtin_amdgcn_mfma_f32_16x16x32_bf16(a[mi][ks], b[ni][ks],
                                                                acc[mi][ni], 0, 0, 0);
  }

  // epilogue: pair (ni=2p, 2p+1) -> silu(g)*h at hidden col n0/2 + ((wc*4+2p)>>1)*16 + l15
  #pragma unroll
  for (int mi = 0; mi < 4; mi++) {
    #pragma unroll
    for (int p = 0; p < 2; p++) {
      const int col = n0 / 2 + ((wc * 4 + 2 * p) >> 1) * 16 + l15;
      #pragma unroll
      for (int r = 0; r < 4; r++) {
        const int row = m0 + wr * 64 + mi * 16 + l4 * 4 + r;
        const float g = acc[mi][2 * p][r];
        const float h = acc[mi][2 * p + 1][r];
        const float sg = g / (1.0f + __expf(-g));
        Cout[(size_t)row * 5632 + col] = f2bf(sg * h);
      }
    }
  }
}

// ---------- 128x64-tile GEMM, BK=64, for N=2048 outputs (proj / mlp_proj) ----------
template <int EPI>
__global__ __launch_bounds__(256, 3) void gemm_bt64(const uint16_t* __restrict__ A,
                                                    const uint16_t* __restrict__ BT,
                                                    void* __restrict__ Cout,
                                                    const void* __restrict__ RES,
                                                    int M, int N, int K) {
  __shared__ uint16_t As[128 * 64];  // 16 KB
  __shared__ uint16_t Bs[64 * 64];   //  8 KB
  const int tid = threadIdx.x;
  const int lane = tid & 63;
  const int w = tid >> 6;
  const int l15 = lane & 15, l4 = lane >> 4;
  const int m0 = blockIdx.y * 128, n0 = blockIdx.x * 64;

  f32x4 acc[2][4];
  #pragma unroll
  for (int i = 0; i < 2; i++)
    #pragma unroll
    for (int j = 0; j < 4; j++) acc[i][j] = 0.0f;

  for (int kk = 0; kk < K; kk += 64) {
    __syncthreads();
    #pragma unroll
    for (int s = 0; s < 4; s++) {
      const int bu = s * 256 + w * 64;
      const int u = bu + lane;
      const int row = u >> 3;
      const int ch = (u & 7) ^ (row & 7);
      async_copy16(A + (size_t)(m0 + row) * K + kk + ch * 8, (char*)As + bu * 16);
    }
    #pragma unroll
    for (int s = 0; s < 2; s++) {
      const int bu = s * 256 + w * 64;
      const int u = bu + lane;
      const int row = u >> 3;              // 0..63
      const int ch = (u & 7) ^ (row & 7);
      async_copy16(BT + (size_t)(n0 + row) * K + kk + ch * 8, (char*)Bs + bu * 16);
    }
    __syncthreads();
    bf8_t a[2][2], b[4][2];
    #pragma unroll
    for (int mi = 0; mi < 2; mi++)
      #pragma unroll
      for (int ks = 0; ks < 2; ks++) {
        const int R = w * 32 + mi * 16 + l15;
        a[mi][ks] = *(const bf8_t*)((const char*)As + R * 128 + (((ks * 4 + l4) ^ (R & 7)) * 16));
      }
    #pragma unroll
    for (int ni = 0; ni < 4; ni++)
      #pragma unroll
      for (int ks = 0; ks < 2; ks++) {
        const int R = ni * 16 + l15;
        b[ni][ks] = *(const bf8_t*)((const char*)Bs + R * 128 + (((ks * 4 + l4) ^ (R & 7)) * 16));
      }
    #pragma unroll
    for (int mi = 0; mi < 2; mi++)
      #pragma unroll
      for (int ni = 0; ni < 4; ni++)
        #pragma unroll
        for (int ks = 0; ks < 2; ks++)
          acc[mi][ni] = __builtin_amdgcn_mfma_f32_16x16x32_bf16(a[mi][ks], b[ni][ks],
                                                                acc[mi][ni], 0, 0, 0);
  }

  #pragma unroll
  for (int mi = 0; mi < 2; mi++) {
    #pragma unroll
    for (int ni = 0; ni < 4; ni++) {
      #pragma unroll
      for (int r = 0; r < 4; r++) {
        const int row = m0 + w * 32 + mi * 16 + l4 * 4 + r;
        const int col = n0 + ni * 16 + l15;
        gemm_epi(EPI, Cout, RES, (size_t)row * N + col, acc[mi][ni][r]);
      }
    }
  }
}

// ---------- flash attention, kv-split partials (unchanged from R8/R10) ----------
#define PART_STRIDE (64 * 128 + 128)
__global__ __launch_bounds__(256, 2) void attn_part(const uint16_t* __restrict__ qkv,
                                                    const uint16_t* __restrict__ vT,
                                                    const float* __restrict__ alibi,
                                                    float* __restrict__ part) {
  const int p = blockIdx.x;
  const int qt = 31 - blockIdx.y;
  const int h = blockIdx.z;
  const int c = (qt + 4) >> 2;
  const int start = p * c;
  const int end = min((p + 1) * c, qt + 1);
  if (start >= end) return;

  const int tid = threadIdx.x;
  const int lane = tid & 63;
  const int w = tid >> 6;
  const int l15 = lane & 15, l4 = lane >> 4;

  __shared__ uint16_t Ks[2][64 * 128];
  __shared__ uint16_t Vs[2][128 * 64];
  __shared__ uint16_t Ps[4][16 * 64];

  const float scale = 0.08838834764831845f;

  auto stage = [&](int kv0, int b) {
    #pragma unroll
    for (int i = 0; i < 4; i++) {
      const int u = tid + i * 256;
      const int r = u >> 4;
      const int cc = (u & 15) ^ ((r & 7) ^ ((r >> 3) & 7));
      async_copy16(qkv + (size_t)(kv0 + r) * 6144 + 2048 + h * 128 + cc * 8,
                   (char*)Ks[b] + u * 16);
    }
    #pragma unroll
    for (int i = 0; i < 4; i++) {
      const int u = tid + i * 256;
      const int r = u >> 3;
      const int cc = (u & 7) ^ (r & 7);
      async_copy16(vT + (size_t)(h * 128 + r) * 2048 + kv0 + cc * 8,
                   (char*)Vs[b] + u * 16);
    }
  };
  auto load_al = [&](int kv0, float (&al)[4][4]) {
    #pragma unroll
    for (int r = 0; r < 4; r++) {
      const size_t rowb = ((size_t)h * 2048 + (qt * 64 + w * 16 + l4 * 4 + r)) * 2048;
      #pragma unroll
      for (int nf = 0; nf < 4; nf++)
        al[nf][r] = alibi[rowb + kv0 + nf * 16 + l15];
    }
  };

  const int qrow = qt * 64 + w * 16 + l15;
  bf8_t qf[4];
  #pragma unroll
  for (int kc = 0; kc < 4; kc++)
    qf[kc] = *(const bf8_t*)(qkv + (size_t)qrow * 6144 + h * 128 + kc * 32 + l4 * 8);

  f32x4 accy[8];
  #pragma unroll
  for (int i = 0; i < 8; i++) accy[i] = 0.0f;
  float mrun[4], lrun[4];
  #pragma unroll
  for (int r = 0; r < 4; r++) { mrun[r] = -1e30f; lrun[r] = 0.0f; }

  stage(start * 64, 0);
  float al[4][4];
  load_al(start * 64, al);

  for (int kvt = start; kvt < end; kvt++) {
    const int b = (kvt - start) & 1;
    const int kv0 = kvt * 64;
    __syncthreads();

    const int kvn = (kvt + 1 < end) ? (kvt + 1) : kvt;
    float aln[4][4];
    load_al(kvn * 64, aln);
    stage(kvn * 64, b ^ 1);

    float s[4][4];
    #pragma unroll
    for (int nf = 0; nf < 4; nf++) {
      f32x4 sa = 0.0f;
      const int krow = nf * 16 + l15;
      __builtin_amdgcn_s_setprio(1);
      #pragma unroll
      for (int kc = 0; kc < 4; kc++) {
        bf8_t kb = *(const bf8_t*)((const char*)Ks[b] +
                                   ((krow * 256 + kc * 64 + l4 * 16) ^ swz(krow)));
        sa = __builtin_amdgcn_mfma_f32_16x16x32_bf16(qf[kc], kb, sa, 0, 0, 0);
      }
      __builtin_amdgcn_s_setprio(0);
      const int kvcol = kv0 + nf * 16 + l15;
      #pragma unroll
      for (int r = 0; r < 4; r++) {
        const int q = qt * 64 + w * 16 + l4 * 4 + r;
        float sv = sa[r] * scale + al[nf][r];
        if (kvcol > q) sv = -1e30f;
        s[nf][r] = sv;
      }
    }

    #pragma unroll
    for (int r = 0; r < 4; r++) {
      float rm = fmaxf(fmaxf(s[0][r], s[1][r]), fmaxf(s[2][r], s[3][r]));
      rm = fmaxf(rm, __shfl_xor(rm, 1));
      rm = fmaxf(rm, __shfl_xor(rm, 2));
      rm = fmaxf(rm, __shfl_xor(rm, 4));
      rm = fmaxf(rm, __shfl_xor(rm, 8));
      const float mnew = fmaxf(mrun[r], rm);
      const float alpha = __expf(mrun[r] - mnew);
      mrun[r] = mnew;
      float rs = 0.0f;
      #pragma unroll
      for (int nf = 0; nf < 4; nf++) {
        const float pp = __expf(s[nf][r] - mnew);
        s[nf][r] = pp;
        rs += pp;
      }
      rs += __shfl_xor(rs, 1);
      rs += __shfl_xor(rs, 2);
      rs += __shfl_xor(rs, 4);
      rs += __shfl_xor(rs, 8);
      lrun[r] = lrun[r] * alpha + rs;
      #pragma unroll
      for (int df = 0; df < 8; df++) accy[df][r] *= alpha;
    }

    #pragma unroll
    for (int nf = 0; nf < 4; nf++) {
      #pragma unroll
      for (int r = 0; r < 4; r++) {
        const int rq = l4 * 4 + r;
        const int bo = (rq * 128 + (nf * 16 + l15) * 2) ^ vswz(rq);
        *(uint16_t*)((char*)Ps[w] + bo) = f2bf(s[nf][r]);
      }
    }

    __builtin_amdgcn_s_setprio(1);
    #pragma unroll
    for (int kk = 0; kk < 2; kk++) {
      bf8_t pa = *(const bf8_t*)((const char*)Ps[w] +
                                 ((l15 * 128 + kk * 64 + l4 * 16) ^ vswz(l15)));
      #pragma unroll
      for (int df = 0; df < 8; df++) {
        const int vr = df * 16 + l15;
        bf8_t vb = *(const bf8_t*)((const char*)Vs[b] +
                                   ((vr * 128 + kk * 64 + l4 * 16) ^ vswz(vr)));
        accy[df] = __builtin_amdgcn_mfma_f32_16x16x32_bf16(pa, vb, accy[df], 0, 0, 0);
      }
    }
    __builtin_amdgcn_s_setprio(0);

    #pragma unroll
    for (int nf = 0; nf < 4; nf++)
      #pragma unroll
      for (int r = 0; r < 4; r++) al[nf][r] = aln[nf][r];
  }

  float* pb = part + (size_t)(((h * 32 + qt) * 4) + p) * PART_STRIDE;
  #pragma unroll
  for (int df = 0; df < 8; df++) {
    #pragma unroll
    for (int r = 0; r < 4; r++) {
      const int row = w * 16 + l4 * 4 + r;
      pb[row * 128 + df * 16 + l15] = accy[df][r];
    }
  }
  if (l15 == 0) {
    #pragma unroll
    for (int r = 0; r < 4; r++) {
      const int row = w * 16 + l4 * 4 + r;
      pb[8192 + row] = mrun[r];
      pb[8192 + 64 + row] = lrun[r];
    }
  }
}

// ---------- merge kv-split partials -> Y bf16 [2048][2048] ----------
__global__ __launch_bounds__(256) void attn_merge(const float* __restrict__ part,
                                                  uint16_t* __restrict__ Y) {
  const int qt = blockIdx.x;
  const int h = blockIdx.y;
  const int c = (qt + 4) >> 2;
  const int cnt = (qt + c) / c;
  const int tid = threadIdx.x;
  const int row = tid >> 2;
  const int cg = (tid & 3) * 32;

  const float* pb = part + (size_t)((h * 32 + qt) * 4) * PART_STRIDE;

  float m_p[4], w_p[4];
  float M = -1e30f;
  for (int p = 0; p < cnt; p++) {
    m_p[p] = pb[p * PART_STRIDE + 8192 + row];
    M = fmaxf(M, m_p[p]);
  }
  float L = 0.0f;
  for (int p = 0; p < cnt; p++) {
    w_p[p] = __expf(m_p[p] - M);
    L += w_p[p] * pb[p * PART_STRIDE + 8192 + 64 + row];
  }
  const float invL = 1.0f / L;

  uint16_t* yr = Y + (size_t)(qt * 64 + row) * 2048 + h * 128 + cg;
  #pragma unroll
  for (int j = 0; j < 32; j += 8) {
    f32x4 s0 = 0.0f, s1 = 0.0f;
    for (int p = 0; p < cnt; p++) {
      const float* ap = pb + p * PART_STRIDE + row * 128 + cg + j;
      s0 += w_p[p] * *(const f32x4*)ap;
      s1 += w_p[p] * *(const f32x4*)(ap + 4);
    }
    u16x8 o;
    #pragma unroll
    for (int e = 0; e < 4; e++) { o[e] = f2bf(s0[e] * invL); o[e + 4] = f2bf(s1[e] * invL); }
    *(u16x8*)(yr + j) = o;
  }
}

// ---------- launch ----------
extern "C" void kernel_launch(void* const* d_in, const int* in_sizes, int n_in,
                              void* d_out, int out_size, void* d_ws, size_t ws_size,
                              hipStream_t stream) {
  const float* x      = (const float*)d_in[0];
  const float* alibi  = (const float*)d_in[1];
  const float* w_attn = (const float*)d_in[2];
  const float* w_proj = (const float*)d_in[3];
  const float* w_fc1  = (const float*)d_in[4];
  const float* w_fc2  = (const float*)d_in[5];
  const float* w_mp   = (const float*)d_in[6];
  const float* rms1   = (const float*)d_in[7];
  const float* rms2   = (const float*)d_in[8];
  float* out = (float*)d_out;

  char* ws = (char*)d_ws;
  uint16_t* xn      = (uint16_t*)(ws + 0);          //  8.39 MB
  uint16_t* qkv     = (uint16_t*)(ws + 8388608);    // 25.17 MB
  uint16_t* y       = (uint16_t*)(ws + 33554432);   //  8.39 MB
  uint16_t* hbuf    = (uint16_t*)(ws + 65011712);   // 23.07 MB
  uint16_t* wt_attn = (uint16_t*)(ws + 88080384);   // 25.17 MB
  uint16_t* wt_proj = (uint16_t*)(ws + 113246208);  //  8.39 MB
  uint16_t* wt_cat  = (uint16_t*)(ws + 121634816);  // 46.14 MB [11264][2048] interleaved
  uint16_t* wt_mp   = (uint16_t*)(ws + 167772160);  // 23.07 MB
  uint16_t* vT      = (uint16_t*)(ws + 190840832);  //  8.39 MB
  float*    part    = (float*)(ws + 199229440);     // 68.2 MB

  transpose_all<<<12544, 256, 0, stream>>>(w_attn, w_proj, w_fc1, w_fc2, w_mp,
                                           wt_attn, wt_proj, wt_cat, wt_mp);

  rmsnorm_kernel<<<2048, 256, 0, stream>>>(x, rms1, xn);

  gemm_bt<EPI_BF16><<<dim3(6144 / 128, 2048 / 128), 256, 0, stream>>>(
      xn, wt_attn, qkv, nullptr, 2048, 6144, 2048);

  transpose_v<<<dim3(32, 32), 256, 0, stream>>>(qkv, vT);

  attn_part<<<dim3(4, 32, 16), 256, 0, stream>>>(qkv, vT, alibi, part);

  attn_merge<<<dim3(32, 16), 256, 0, stream>>>(part, y);

  gemm_bt64<EPI_ADDF32><<<dim3(2048 / 64, 2048 / 128), 256, 0, stream>>>(
      y, wt_proj, out, x, 2048, 2048, 2048);

  rmsnorm_kernel<<<2048, 256, 0, stream>>>(out, rms2, xn);

  // fused fc1+fc2 over interleaved wt_cat: hbuf = silu(xn@w_fc1) * (xn@w_fc2)
  gemm_cat<<<dim3(11264 / 128, 2048 / 128), 256, 0, stream>>>(
      xn, wt_cat, hbuf, 2048, 2048);

  gemm_bt64<EPI_ADDF32><<<dim3(2048 / 64, 2048 / 128), 256, 0, stream>>>(
      hbuf, wt_mp, out, out, 2048, 2048, 5632);
}

// Round 13
// 451.862 us; speedup vs baseline: 1.1359x; 1.0568x over previous
//
#include <hip/hip_runtime.h>
#include <stdint.h>

// ---------- types ----------
typedef __attribute__((ext_vector_type(4))) float f32x4;
typedef __attribute__((ext_vector_type(8))) __bf16 bf8_t;     // MFMA A/B fragment (8 bf16 = 4 VGPR)
typedef __attribute__((ext_vector_type(8))) uint16_t u16x8;   // raw 16B bf16 load/store

typedef __attribute__((address_space(1))) uint8_t as1_u8;
typedef __attribute__((address_space(3))) uint8_t as3_u8;

__device__ inline void async_copy16(const void* g, void* l) {
  __builtin_amdgcn_global_load_lds((const as1_u8*)g, (as3_u8*)l, 16, 0, 0);
}

__device__ inline uint16_t f2bf(float f) {
  uint32_t u = __builtin_bit_cast(uint32_t, f);
  u = (u + 0x7fff + ((u >> 16) & 1)) >> 16;
  return (uint16_t)u;
}
__device__ inline float bf2f(uint16_t h) {
  uint32_t u = ((uint32_t)h) << 16;
  return __builtin_bit_cast(float, u);
}
// XOR swizzle for 256B-row bf16 LDS tiles (16 chunks of 16B per row)
__device__ inline int swz(int r) { return (((r & 7) ^ ((r >> 3) & 7)) << 4); }
// XOR swizzle for 128B-row bf16 LDS tiles (8 chunks of 16B per row)
__device__ inline int vswz(int r) { return ((r & 7) << 4); }

// attn partial: bf16 acc[64][128] + f32 m[64] + f32 l[64]
#define PART_BYTES (64 * 128 * 2 + 128 * 4)

// ---------- rmsnorm: f32 [2048] row -> bf16 ----------
__global__ __launch_bounds__(256) void rmsnorm_kernel(const float* __restrict__ X,
                                                      const float* __restrict__ S,
                                                      uint16_t* __restrict__ O) {
  const int row = blockIdx.x;
  const int tid = threadIdx.x;
  const float* xr = X + (size_t)row * 2048;
  float4 v1 = ((const float4*)xr)[tid * 2];
  float4 v2 = ((const float4*)xr)[tid * 2 + 1];
  float ss = v1.x * v1.x + v1.y * v1.y + v1.z * v1.z + v1.w * v1.w +
             v2.x * v2.x + v2.y * v2.y + v2.z * v2.z + v2.w * v2.w;
  #pragma unroll
  for (int m = 1; m < 64; m <<= 1) ss += __shfl_xor(ss, m);
  __shared__ float wsum[4];
  if ((tid & 63) == 0) wsum[tid >> 6] = ss;
  __syncthreads();
  float tot = wsum[0] + wsum[1] + wsum[2] + wsum[3];
  float inv = rsqrtf(tot * (1.0f / 2048.0f) + 1e-5f);
  const int base = tid * 8;
  const float* sc = S + base;
  float xs[8] = {v1.x, v1.y, v1.z, v1.w, v2.x, v2.y, v2.z, v2.w};
  u16x8 o;
  #pragma unroll
  for (int j = 0; j < 8; j++) o[j] = f2bf(xs[j] * inv * sc[j]);
  *(u16x8*)(O + (size_t)row * 2048 + base) = o;
}

// ---------- transpose+convert: one 64x64 tile; catoff<0 -> linear rows,
// else interleaved-cat row: catrow = (n>>4)*32 + catoff + (n&15) ----------
__device__ inline void transpose_tile2(const float* __restrict__ W, uint16_t* __restrict__ WT,
                                       int K, int N, int bx, int by, int tid, int catoff) {
  __shared__ float tile[64][65];
  const int n0 = bx * 64, k0 = by * 64;
  const int lr = tid >> 4;
  const int lc = (tid & 15) * 4;
  #pragma unroll
  for (int i = 0; i < 4; i++) {
    const float4 v = *(const float4*)&W[(size_t)(k0 + lr + i * 16) * N + n0 + lc];
    tile[lr + i * 16][lc] = v.x;
    tile[lr + i * 16][lc + 1] = v.y;
    tile[lr + i * 16][lc + 2] = v.z;
    tile[lr + i * 16][lc + 3] = v.w;
  }
  __syncthreads();
  const int tn = tid >> 3;
  const int tk = (tid & 7) * 8;
  #pragma unroll
  for (int i = 0; i < 2; i++) {
    u16x8 o;
    #pragma unroll
    for (int j = 0; j < 8; j++) o[j] = f2bf(tile[tk + j][tn + i * 32]);
    const int n = n0 + tn + i * 32;
    const int row = (catoff < 0) ? n : (((n >> 4) << 5) + catoff + (n & 15));
    *(u16x8*)&WT[(size_t)row * K + k0 + tk] = o;
  }
}

// one launch for all 5 weight transposes (fc1/fc2 -> interleaved wt_cat)
__global__ __launch_bounds__(256) void transpose_all(
    const float* __restrict__ w_attn, const float* __restrict__ w_proj,
    const float* __restrict__ w_fc1, const float* __restrict__ w_fc2,
    const float* __restrict__ w_mp,
    uint16_t* __restrict__ wt_attn, uint16_t* __restrict__ wt_proj,
    uint16_t* __restrict__ wt_cat, uint16_t* __restrict__ wt_mp) {
  int idx = blockIdx.x;
  const int tid = threadIdx.x;
  if (idx < 3072) {                       // w_attn: 96 x 32 tiles
    transpose_tile2(w_attn, wt_attn, 2048, 6144, idx % 96, idx / 96, tid, -1);
  } else if (idx < 4096) {                // w_proj: 32 x 32
    idx -= 3072;
    transpose_tile2(w_proj, wt_proj, 2048, 2048, idx % 32, idx / 32, tid, -1);
  } else if (idx < 6912) {                // w_fc1: 88 x 32 -> cat even 16-groups
    idx -= 4096;
    transpose_tile2(w_fc1, wt_cat, 2048, 5632, idx % 88, idx / 88, tid, 0);
  } else if (idx < 9728) {                // w_fc2: 88 x 32 -> cat odd 16-groups
    idx -= 6912;
    transpose_tile2(w_fc2, wt_cat, 2048, 5632, idx % 88, idx / 88, tid, 16);
  } else {                                // w_mp: 32 x 88 (K=5632)
    idx -= 9728;
    transpose_tile2(w_mp, wt_mp, 5632, 2048, idx % 32, idx / 32, tid, -1);
  }
}

// ---------- transpose V third of qkv: bf16 [2048 t][4096+c] -> vT [2048 c][2048 t] ----------
__global__ __launch_bounds__(256) void transpose_v(const uint16_t* __restrict__ qkv,
                                                   uint16_t* __restrict__ vT) {
  __shared__ uint16_t tile[64][68];
  const int t0 = blockIdx.x * 64;
  const int c0 = blockIdx.y * 64;
  const int tid = threadIdx.x;
  const int lr = tid >> 3;
  const int lc = (tid & 7) * 8;
  #pragma unroll
  for (int i = 0; i < 2; i++) {
    const int r = lr + i * 32;
    u16x8 v = *(const u16x8*)&qkv[(size_t)(t0 + r) * 6144 + 4096 + c0 + lc];
    #pragma unroll
    for (int j = 0; j < 8; j++) tile[lc + j][r] = v[j];
  }
  __syncthreads();
  #pragma unroll
  for (int i = 0; i < 2; i++) {
    const int c = lr + i * 32;
    u16x8 o = *(const u16x8*)&tile[c][lc];
    *(u16x8*)&vT[(size_t)(c0 + c) * 2048 + t0 + lc] = o;
  }
}

// ---------- GEMM epilogue modes ----------
enum { EPI_BF16 = 0, EPI_ADDF32 = 1, EPI_SILUMUL = 2 };

__device__ inline void gemm_epi(int EPI, void* Cout, const void* RES, size_t idx, float v) {
  if (EPI == EPI_BF16) {
    ((uint16_t*)Cout)[idx] = f2bf(v);
  } else if (EPI == EPI_ADDF32) {
    ((float*)Cout)[idx] = ((const float*)RES)[idx] + v;
  } else {
    const float g = bf2f(((const uint16_t*)RES)[idx]);
    const float sg = g / (1.0f + __expf(-g));
    ((uint16_t*)Cout)[idx] = f2bf(sg * v);
  }
}

// ---------- 128x128 GEMM, BK=64, 3 blocks/CU (per-ks frags keep VGPR < 170) ----------
template <int EPI>
__global__ __launch_bounds__(256, 3) void gemm_bt(const uint16_t* __restrict__ A,
                                                  const uint16_t* __restrict__ BT,
                                                  void* __restrict__ Cout,
                                                  const void* __restrict__ RES,
                                                  int M, int N, int K) {
  __shared__ uint16_t As[128 * 64];  // 16 KB
  __shared__ uint16_t Bs[128 * 64];  // 16 KB
  const int tid = threadIdx.x;
  const int lane = tid & 63;
  const int w = tid >> 6;
  const int l15 = lane & 15, l4 = lane >> 4;
  const int m0 = blockIdx.y * 128, n0 = blockIdx.x * 128;
  const int wr = w >> 1, wc = w & 1;

  f32x4 acc[4][4];
  #pragma unroll
  for (int i = 0; i < 4; i++)
    #pragma unroll
    for (int j = 0; j < 4; j++) acc[i][j] = 0.0f;

  for (int kk = 0; kk < K; kk += 64) {
    __syncthreads();
    #pragma unroll
    for (int s = 0; s < 4; s++) {
      const int bu = s * 256 + w * 64;     // wave-uniform 16B-chunk base
      const int u = bu + lane;             // chunk 0..1023
      const int row = u >> 3;
      const int ch = (u & 7) ^ (row & 7);  // pre-swizzled source chunk
      async_copy16(A + (size_t)(m0 + row) * K + kk + ch * 8, (char*)As + bu * 16);
      async_copy16(BT + (size_t)(n0 + row) * K + kk + ch * 8, (char*)Bs + bu * 16);
    }
    __syncthreads();
    #pragma unroll
    for (int ks = 0; ks < 2; ks++) {
      bf8_t a[4], b[4];
      #pragma unroll
      for (int mi = 0; mi < 4; mi++) {
        const int R = wr * 64 + mi * 16 + l15;
        a[mi] = *(const bf8_t*)((const char*)As + R * 128 + (((ks * 4 + l4) ^ (R & 7)) * 16));
      }
      #pragma unroll
      for (int ni = 0; ni < 4; ni++) {
        const int R = wc * 64 + ni * 16 + l15;
        b[ni] = *(const bf8_t*)((const char*)Bs + R * 128 + (((ks * 4 + l4) ^ (R & 7)) * 16));
      }
      #pragma unroll
      for (int mi = 0; mi < 4; mi++)
        #pragma unroll
        for (int ni = 0; ni < 4; ni++)
          acc[mi][ni] = __builtin_amdgcn_mfma_f32_16x16x32_bf16(a[mi], b[ni], acc[mi][ni], 0, 0, 0);
    }
  }

  #pragma unroll
  for (int mi = 0; mi < 4; mi++) {
    #pragma unroll
    for (int ni = 0; ni < 4; ni++) {
      #pragma unroll
      for (int r = 0; r < 4; r++) {
        const int row = m0 + wr * 64 + mi * 16 + l4 * 4 + r;
        const int col = n0 + wc * 64 + ni * 16 + l15;
        gemm_epi(EPI, Cout, RES, (size_t)row * N + col, acc[mi][ni][r]);
      }
    }
  }
}

// ---------- fused fc1+fc2: C = silu(A@W1) * (A@W2) over interleaved wt_cat ----------
__global__ __launch_bounds__(256, 3) void gemm_cat(const uint16_t* __restrict__ A,
                                                   const uint16_t* __restrict__ BT,
                                                   uint16_t* __restrict__ Cout,
                                                   int M, int K) {
  __shared__ uint16_t As[128 * 64];
  __shared__ uint16_t Bs[128 * 64];
  const int tid = threadIdx.x;
  const int lane = tid & 63;
  const int w = tid >> 6;
  const int l15 = lane & 15, l4 = lane >> 4;
  const int m0 = blockIdx.y * 128, n0 = blockIdx.x * 128;  // n0 in cat space
  const int wr = w >> 1, wc = w & 1;

  f32x4 acc[4][4];
  #pragma unroll
  for (int i = 0; i < 4; i++)
    #pragma unroll
    for (int j = 0; j < 4; j++) acc[i][j] = 0.0f;

  for (int kk = 0; kk < K; kk += 64) {
    __syncthreads();
    #pragma unroll
    for (int s = 0; s < 4; s++) {
      const int bu = s * 256 + w * 64;
      const int u = bu + lane;
      const int row = u >> 3;
      const int ch = (u & 7) ^ (row & 7);
      async_copy16(A + (size_t)(m0 + row) * K + kk + ch * 8, (char*)As + bu * 16);
      async_copy16(BT + (size_t)(n0 + row) * K + kk + ch * 8, (char*)Bs + bu * 16);
    }
    __syncthreads();
    #pragma unroll
    for (int ks = 0; ks < 2; ks++) {
      bf8_t a[4], b[4];
      #pragma unroll
      for (int mi = 0; mi < 4; mi++) {
        const int R = wr * 64 + mi * 16 + l15;
        a[mi] = *(const bf8_t*)((const char*)As + R * 128 + (((ks * 4 + l4) ^ (R & 7)) * 16));
      }
      #pragma unroll
      for (int ni = 0; ni < 4; ni++) {
        const int R = wc * 64 + ni * 16 + l15;
        b[ni] = *(const bf8_t*)((const char*)Bs + R * 128 + (((ks * 4 + l4) ^ (R & 7)) * 16));
      }
      #pragma unroll
      for (int mi = 0; mi < 4; mi++)
        #pragma unroll
        for (int ni = 0; ni < 4; ni++)
          acc[mi][ni] = __builtin_amdgcn_mfma_f32_16x16x32_bf16(a[mi], b[ni], acc[mi][ni], 0, 0, 0);
    }
  }

  // epilogue: pair (ni=2p, 2p+1) -> silu(g)*h at hidden col n0/2 + ((wc*4+2p)>>1)*16 + l15
  #pragma unroll
  for (int mi = 0; mi < 4; mi++) {
    #pragma unroll
    for (int p = 0; p < 2; p++) {
      const int col = n0 / 2 + ((wc * 4 + 2 * p) >> 1) * 16 + l15;
      #pragma unroll
      for (int r = 0; r < 4; r++) {
        const int row = m0 + wr * 64 + mi * 16 + l4 * 4 + r;
        const float g = acc[mi][2 * p][r];
        const float h = acc[mi][2 * p + 1][r];
        const float sg = g / (1.0f + __expf(-g));
        Cout[(size_t)row * 5632 + col] = f2bf(sg * h);
      }
    }
  }
}

// ---------- 128x64-tile GEMM, BK=64, for N=2048 outputs (proj / mlp_proj) ----------
template <int EPI>
__global__ __launch_bounds__(256, 3) void gemm_bt64(const uint16_t* __restrict__ A,
                                                    const uint16_t* __restrict__ BT,
                                                    void* __restrict__ Cout,
                                                    const void* __restrict__ RES,
                                                    int M, int N, int K) {
  __shared__ uint16_t As[128 * 64];  // 16 KB
  __shared__ uint16_t Bs[64 * 64];   //  8 KB
  const int tid = threadIdx.x;
  const int lane = tid & 63;
  const int w = tid >> 6;
  const int l15 = lane & 15, l4 = lane >> 4;
  const int m0 = blockIdx.y * 128, n0 = blockIdx.x * 64;

  f32x4 acc[2][4];
  #pragma unroll
  for (int i = 0; i < 2; i++)
    #pragma unroll
    for (int j = 0; j < 4; j++) acc[i][j] = 0.0f;

  for (int kk = 0; kk < K; kk += 64) {
    __syncthreads();
    #pragma unroll
    for (int s = 0; s < 4; s++) {
      const int bu = s * 256 + w * 64;
      const int u = bu + lane;
      const int row = u >> 3;
      const int ch = (u & 7) ^ (row & 7);
      async_copy16(A + (size_t)(m0 + row) * K + kk + ch * 8, (char*)As + bu * 16);
    }
    #pragma unroll
    for (int s = 0; s < 2; s++) {
      const int bu = s * 256 + w * 64;
      const int u = bu + lane;
      const int row = u >> 3;              // 0..63
      const int ch = (u & 7) ^ (row & 7);
      async_copy16(BT + (size_t)(n0 + row) * K + kk + ch * 8, (char*)Bs + bu * 16);
    }
    __syncthreads();
    bf8_t a[2][2], b[4][2];
    #pragma unroll
    for (int mi = 0; mi < 2; mi++)
      #pragma unroll
      for (int ks = 0; ks < 2; ks++) {
        const int R = w * 32 + mi * 16 + l15;
        a[mi][ks] = *(const bf8_t*)((const char*)As + R * 128 + (((ks * 4 + l4) ^ (R & 7)) * 16));
      }
    #pragma unroll
    for (int ni = 0; ni < 4; ni++)
      #pragma unroll
      for (int ks = 0; ks < 2; ks++) {
        const int R = ni * 16 + l15;
        b[ni][ks] = *(const bf8_t*)((const char*)Bs + R * 128 + (((ks * 4 + l4) ^ (R & 7)) * 16));
      }
    #pragma unroll
    for (int mi = 0; mi < 2; mi++)
      #pragma unroll
      for (int ni = 0; ni < 4; ni++)
        #pragma unroll
        for (int ks = 0; ks < 2; ks++)
          acc[mi][ni] = __builtin_amdgcn_mfma_f32_16x16x32_bf16(a[mi][ks], b[ni][ks],
                                                                acc[mi][ni], 0, 0, 0);
  }

  #pragma unroll
  for (int mi = 0; mi < 2; mi++) {
    #pragma unroll
    for (int ni = 0; ni < 4; ni++) {
      #pragma unroll
      for (int r = 0; r < 4; r++) {
        const int row = m0 + w * 32 + mi * 16 + l4 * 4 + r;
        const int col = n0 + ni * 16 + l15;
        gemm_epi(EPI, Cout, RES, (size_t)row * N + col, acc[mi][ni][r]);
      }
    }
  }
}

// ---------- flash attention, kv-split partials (bf16 acc + f32 m/l) ----------
__global__ __launch_bounds__(256, 2) void attn_part(const uint16_t* __restrict__ qkv,
                                                    const uint16_t* __restrict__ vT,
                                                    const float* __restrict__ alibi,
                                                    char* __restrict__ part) {
  const int p = blockIdx.x;
  const int qt = 31 - blockIdx.y;
  const int h = blockIdx.z;
  const int c = (qt + 4) >> 2;
  const int start = p * c;
  const int end = min((p + 1) * c, qt + 1);
  if (start >= end) return;

  const int tid = threadIdx.x;
  const int lane = tid & 63;
  const int w = tid >> 6;
  const int l15 = lane & 15, l4 = lane >> 4;

  __shared__ uint16_t Ks[2][64 * 128];
  __shared__ uint16_t Vs[2][128 * 64];
  __shared__ uint16_t Ps[4][16 * 64];

  const float scale = 0.08838834764831845f;

  auto stage = [&](int kv0, int b) {
    #pragma unroll
    for (int i = 0; i < 4; i++) {
      const int u = tid + i * 256;
      const int r = u >> 4;
      const int cc = (u & 15) ^ ((r & 7) ^ ((r >> 3) & 7));
      async_copy16(qkv + (size_t)(kv0 + r) * 6144 + 2048 + h * 128 + cc * 8,
                   (char*)Ks[b] + u * 16);
    }
    #pragma unroll
    for (int i = 0; i < 4; i++) {
      const int u = tid + i * 256;
      const int r = u >> 3;
      const int cc = (u & 7) ^ (r & 7);
      async_copy16(vT + (size_t)(h * 128 + r) * 2048 + kv0 + cc * 8,
                   (char*)Vs[b] + u * 16);
    }
  };
  auto load_al = [&](int kv0, float (&al)[4][4]) {
    #pragma unroll
    for (int r = 0; r < 4; r++) {
      const size_t rowb = ((size_t)h * 2048 + (qt * 64 + w * 16 + l4 * 4 + r)) * 2048;
      #pragma unroll
      for (int nf = 0; nf < 4; nf++)
        al[nf][r] = alibi[rowb + kv0 + nf * 16 + l15];
    }
  };

  const int qrow = qt * 64 + w * 16 + l15;
  bf8_t qf[4];
  #pragma unroll
  for (int kc = 0; kc < 4; kc++)
    qf[kc] = *(const bf8_t*)(qkv + (size_t)qrow * 6144 + h * 128 + kc * 32 + l4 * 8);

  f32x4 accy[8];
  #pragma unroll
  for (int i = 0; i < 8; i++) accy[i] = 0.0f;
  float mrun[4], lrun[4];
  #pragma unroll
  for (int r = 0; r < 4; r++) { mrun[r] = -1e30f; lrun[r] = 0.0f; }

  stage(start * 64, 0);
  float al[4][4];
  load_al(start * 64, al);

  for (int kvt = start; kvt < end; kvt++) {
    const int b = (kvt - start) & 1;
    const int kv0 = kvt * 64;
    __syncthreads();

    const int kvn = (kvt + 1 < end) ? (kvt + 1) : kvt;
    float aln[4][4];
    load_al(kvn * 64, aln);
    stage(kvn * 64, b ^ 1);

    float s[4][4];
    #pragma unroll
    for (int nf = 0; nf < 4; nf++) {
      f32x4 sa = 0.0f;
      const int krow = nf * 16 + l15;
      __builtin_amdgcn_s_setprio(1);
      #pragma unroll
      for (int kc = 0; kc < 4; kc++) {
        bf8_t kb = *(const bf8_t*)((const char*)Ks[b] +
                                   ((krow * 256 + kc * 64 + l4 * 16) ^ swz(krow)));
        sa = __builtin_amdgcn_mfma_f32_16x16x32_bf16(qf[kc], kb, sa, 0, 0, 0);
      }
      __builtin_amdgcn_s_setprio(0);
      const int kvcol = kv0 + nf * 16 + l15;
      #pragma unroll
      for (int r = 0; r < 4; r++) {
        const int q = qt * 64 + w * 16 + l4 * 4 + r;
        float sv = sa[r] * scale + al[nf][r];
        if (kvcol > q) sv = -1e30f;
        s[nf][r] = sv;
      }
    }

    #pragma unroll
    for (int r = 0; r < 4; r++) {
      float rm = fmaxf(fmaxf(s[0][r], s[1][r]), fmaxf(s[2][r], s[3][r]));
      rm = fmaxf(rm, __shfl_xor(rm, 1));
      rm = fmaxf(rm, __shfl_xor(rm, 2));
      rm = fmaxf(rm, __shfl_xor(rm, 4));
      rm = fmaxf(rm, __shfl_xor(rm, 8));
      const float mnew = fmaxf(mrun[r], rm);
      const float alpha = __expf(mrun[r] - mnew);
      mrun[r] = mnew;
      float rs = 0.0f;
      #pragma unroll
      for (int nf = 0; nf < 4; nf++) {
        const float pp = __expf(s[nf][r] - mnew);
        s[nf][r] = pp;
        rs += pp;
      }
      rs += __shfl_xor(rs, 1);
      rs += __shfl_xor(rs, 2);
      rs += __shfl_xor(rs, 4);
      rs += __shfl_xor(rs, 8);
      lrun[r] = lrun[r] * alpha + rs;
      #pragma unroll
      for (int df = 0; df < 8; df++) accy[df][r] *= alpha;
    }

    #pragma unroll
    for (int nf = 0; nf < 4; nf++) {
      #pragma unroll
      for (int r = 0; r < 4; r++) {
        const int rq = l4 * 4 + r;
        const int bo = (rq * 128 + (nf * 16 + l15) * 2) ^ vswz(rq);
        *(uint16_t*)((char*)Ps[w] + bo) = f2bf(s[nf][r]);
      }
    }

    __builtin_amdgcn_s_setprio(1);
    #pragma unroll
    for (int kk = 0; kk < 2; kk++) {
      bf8_t pa = *(const bf8_t*)((const char*)Ps[w] +
                                 ((l15 * 128 + kk * 64 + l4 * 16) ^ vswz(l15)));
      #pragma unroll
      for (int df = 0; df < 8; df++) {
        const int vr = df * 16 + l15;
        bf8_t vb = *(const bf8_t*)((const char*)Vs[b] +
                                   ((vr * 128 + kk * 64 + l4 * 16) ^ vswz(vr)));
        accy[df] = __builtin_amdgcn_mfma_f32_16x16x32_bf16(pa, vb, accy[df], 0, 0, 0);
      }
    }
    __builtin_amdgcn_s_setprio(0);

    #pragma unroll
    for (int nf = 0; nf < 4; nf++)
      #pragma unroll
      for (int r = 0; r < 4; r++) al[nf][r] = aln[nf][r];
  }

  char* pb = part + (size_t)(((h * 32 + qt) * 4) + p) * PART_BYTES;
  uint16_t* pa = (uint16_t*)pb;
  #pragma unroll
  for (int df = 0; df < 8; df++) {
    #pragma unroll
    for (int r = 0; r < 4; r++) {
      const int row = w * 16 + l4 * 4 + r;
      pa[row * 128 + df * 16 + l15] = f2bf(accy[df][r]);
    }
  }
  float* pml = (float*)(pb + 16384);
  if (l15 == 0) {
    #pragma unroll
    for (int r = 0; r < 4; r++) {
      const int row = w * 16 + l4 * 4 + r;
      pml[row] = mrun[r];
      pml[64 + row] = lrun[r];
    }
  }
}

// ---------- merge kv-split partials -> Y bf16 [2048][2048] ----------
__global__ __launch_bounds__(256) void attn_merge(const char* __restrict__ part,
                                                  uint16_t* __restrict__ Y) {
  const int qt = blockIdx.x;
  const int h = blockIdx.y;
  const int c = (qt + 4) >> 2;
  const int cnt = (qt + c) / c;
  const int tid = threadIdx.x;
  const int row = tid >> 2;
  const int cg = (tid & 3) * 32;

  const char* pb = part + (size_t)((h * 32 + qt) * 4) * PART_BYTES;

  float m_p[4], w_p[4];
  float M = -1e30f;
  for (int p = 0; p < cnt; p++) {
    m_p[p] = ((const float*)(pb + p * PART_BYTES + 16384))[row];
    M = fmaxf(M, m_p[p]);
  }
  float L = 0.0f;
  for (int p = 0; p < cnt; p++) {
    w_p[p] = __expf(m_p[p] - M);
    L += w_p[p] * ((const float*)(pb + p * PART_BYTES + 16384))[64 + row];
  }
  const float invL = 1.0f / L;

  uint16_t* yr = Y + (size_t)(qt * 64 + row) * 2048 + h * 128 + cg;
  #pragma unroll
  for (int j = 0; j < 32; j += 8) {
    float s[8] = {0, 0, 0, 0, 0, 0, 0, 0};
    for (int p = 0; p < cnt; p++) {
      const u16x8 v = *(const u16x8*)(pb + p * PART_BYTES + (size_t)(row * 128 + cg + j) * 2);
      #pragma unroll
      for (int e = 0; e < 8; e++) s[e] += w_p[p] * bf2f(v[e]);
    }
    u16x8 o;
    #pragma unroll
    for (int e = 0; e < 8; e++) o[e] = f2bf(s[e] * invL);
    *(u16x8*)(yr + j) = o;
  }
}

// ---------- launch ----------
extern "C" void kernel_launch(void* const* d_in, const int* in_sizes, int n_in,
                              void* d_out, int out_size, void* d_ws, size_t ws_size,
                              hipStream_t stream) {
  const float* x      = (const float*)d_in[0];
  const float* alibi  = (const float*)d_in[1];
  const float* w_attn = (const float*)d_in[2];
  const float* w_proj = (const float*)d_in[3];
  const float* w_fc1  = (const float*)d_in[4];
  const float* w_fc2  = (const float*)d_in[5];
  const float* w_mp   = (const float*)d_in[6];
  const float* rms1   = (const float*)d_in[7];
  const float* rms2   = (const float*)d_in[8];
  float* out = (float*)d_out;

  char* ws = (char*)d_ws;
  uint16_t* xn      = (uint16_t*)(ws + 0);          //  8.39 MB
  uint16_t* qkv     = (uint16_t*)(ws + 8388608);    // 25.17 MB
  uint16_t* y       = (uint16_t*)(ws + 33554432);   //  8.39 MB
  uint16_t* hbuf    = (uint16_t*)(ws + 65011712);   // 23.07 MB
  uint16_t* wt_attn = (uint16_t*)(ws + 88080384);   // 25.17 MB
  uint16_t* wt_proj = (uint16_t*)(ws + 113246208);  //  8.39 MB
  uint16_t* wt_cat  = (uint16_t*)(ws + 121634816);  // 46.14 MB [11264][2048] interleaved
  uint16_t* wt_mp   = (uint16_t*)(ws + 167772160);  // 23.07 MB
  uint16_t* vT      = (uint16_t*)(ws + 190840832);  //  8.39 MB
  char*     part    = (char*)(ws + 199229440);      // 2048 x 16896 B = 34.6 MB

  transpose_all<<<12544, 256, 0, stream>>>(w_attn, w_proj, w_fc1, w_fc2, w_mp,
                                           wt_attn, wt_proj, wt_cat, wt_mp);

  rmsnorm_kernel<<<2048, 256, 0, stream>>>(x, rms1, xn);

  gemm_bt<EPI_BF16><<<dim3(6144 / 128, 2048 / 128), 256, 0, stream>>>(
      xn, wt_attn, qkv, nullptr, 2048, 6144, 2048);

  transpose_v<<<dim3(32, 32), 256, 0, stream>>>(qkv, vT);

  attn_part<<<dim3(4, 32, 16), 256, 0, stream>>>(qkv, vT, alibi, part);

  attn_merge<<<dim3(32, 16), 256, 0, stream>>>(part, y);

  gemm_bt64<EPI_ADDF32><<<dim3(2048 / 64, 2048 / 128), 256, 0, stream>>>(
      y, wt_proj, out, x, 2048, 2048, 2048);

  rmsnorm_kernel<<<2048, 256, 0, stream>>>(out, rms2, xn);

  // fused fc1+fc2 over interleaved wt_cat: hbuf = silu(xn@w_fc1) * (xn@w_fc2)
  gemm_cat<<<dim3(11264 / 128, 2048 / 128), 256, 0, stream>>>(
      xn, wt_cat, hbuf, 2048, 2048);

  gemm_bt64<EPI_ADDF32><<<dim3(2048 / 64, 2048 / 128), 256, 0, stream>>>(
      hbuf, wt_mp, out, out, 2048, 2048, 5632);
}